// Round 15
// baseline (1297.505 us; speedup 1.0000x reference)
//
#include <hip/hip_runtime.h>
#include <math.h>

typedef unsigned short u16;
typedef unsigned int u32;
typedef __attribute__((ext_vector_type(8))) short s8v;    // 8 x bf16 (4 VGPRs)
typedef __attribute__((ext_vector_type(16))) float f16f;  // 32x32 MFMA acc

__device__ __forceinline__ float b2f(u16 u){ union{u32 i; float f;} v; v.i=((u32)u)<<16; return v.f; }
__device__ __forceinline__ u16 f2b(float f){ union{float f; u32 i;} v; v.f=f; u32 x=v.i; return (u16)((x + 0x7fffu + ((x>>16)&1u)) >> 16); }
__device__ __forceinline__ float leakyf(float x){ return x>=0.f? x : 0.01f*x; }

#define MFMA32(a,b,c) __builtin_amdgcn_mfma_f32_32x32x16_bf16(a,b,c,0,0,0)

// async global->LDS, 16B per lane, dest = wave-uniform base + lane*16
__device__ __forceinline__ void gl_lds16(const void* g, void* l){
    __builtin_amdgcn_global_load_lds(
        (const __attribute__((address_space(1))) u32*)g,
        (__attribute__((address_space(3))) u32*)l, 16, 0, 0);
}

// ---------------- omic SNN branches (wave-cooperative; validated R14 Output-0) ----------------
struct OmicArgs {
    const float* x[6];
    const float* w1[6];
    int s[6];
};

__global__ __launch_bounds__(256) void omic_kernel(OmicArgs oa,
        const float* __restrict__ sb1, const float* __restrict__ sw2,
        const float* __restrict__ sb2, float* __restrict__ out)
{
    int br = blockIdx.x, t = threadIdx.x;
    int wave = t >> 6, lane = t & 63;
    int s = oa.s[br];
    __shared__ float xs[1536];
    __shared__ float h1[256];
    const float* x = oa.x[br];
    for (int i=t;i<s;i+=256) xs[i] = x[i];
    __syncthreads();
    const float* w1b = oa.w1[br];
    for (int it=0; it<64; ++it){
        int o = (wave<<6) + it;
        const float* wr = w1b + (size_t)o*s;
        float a = 0.f;
        for (int i=lane; i<s; i+=64) a += xs[i]*wr[i];
        #pragma unroll
        for (int off=1;off<64;off<<=1) a += __shfl_xor(a,off,64);
        if (lane==0){
            a += sb1[br*256+o];
            h1[o] = a>0.f ? a : expm1f(a);
        }
    }
    __syncthreads();
    const float* w2b = sw2 + (size_t)br*65536;
    for (int it=0; it<64; ++it){
        int o = (wave<<6) + it;
        const float* wr = w2b + (size_t)o*256;
        float a = 0.f;
        #pragma unroll
        for (int j=0;j<4;++j) a += h1[lane+(j<<6)]*wr[lane+(j<<6)];
        #pragma unroll
        for (int off=1;off<64;off<<=1) a += __shfl_xor(a,off,64);
        if (lane==0){
            a += sb2[br*256+o];
            out[br*256+o] = a>0.f ? a : expm1f(a);
        }
    }
}

// ---------------- batched weight conversion fp32 -> bf16 hi (+lo) ----------------
struct WcSeg { const float* s; u16* dh; u16* dl; int n; };
struct WcArgs { WcSeg seg[6]; };

__global__ __launch_bounds__(256) void wconv(WcArgs a)
{
    WcSeg sg = a.seg[blockIdx.y];
    for (int i = blockIdx.x*256 + threadIdx.x; i < sg.n; i += gridDim.x*256){
        float v = sg.s[i];
        u16 hi = f2b(v);
        sg.dh[i] = hi;
        if (sg.dl) sg.dl[i] = f2b(v - b2f(hi));
    }
}

// ---------------- general MFMA GEMM: C = act(A[M,K]fp32 * W[N,K]^T + b) ----------------
// Block 128x128, 4 waves of 64x64 (2x2 32x32 MFMA tiles). K-chunk 32.
// OUTMODE 0: fp32 out + leaky.  OUTMODE 1: split u16 hi/lo out, no act.
template<int SPLITA, int OUTMODE>
__global__ __launch_bounds__(256,2) void gemm_mfma(
    const float* __restrict__ A, const u16* __restrict__ Wh, const u16* __restrict__ Wl,
    const float* __restrict__ bias,
    float* __restrict__ Cf, u16* __restrict__ Ch, u16* __restrict__ Cl,
    int M, int N, int K)
{
    __shared__ u16 Ash[4096], Asl[4096], Bsh[4096], Bsl[4096];
    int tid = threadIdx.x, w = tid >> 6, lane = tid & 63;
    int l31 = lane & 31, l5 = lane >> 5, lo8 = lane << 3;
    int wr = w >> 1, wc = w & 1;
    int bm = blockIdx.x << 7, bn = blockIdx.y << 7;

    f16f acc[2][2];
    #pragma unroll
    for (int a0=0;a0<2;++a0)
        #pragma unroll
        for (int a1=0;a1<2;++a1)
            #pragma unroll
            for (int e=0;e<16;++e) acc[a0][a1][e] = 0.f;

    for (int k0 = 0; k0 < K; k0 += 32){
        __syncthreads();
        #pragma unroll
        for (int kf = 0; kf < 2; ++kf){
            int kk = k0 + (kf<<4) + (l5<<3);
            const float* ap = A + (size_t)(bm + (w<<5) + l31) * K + kk;
            float4 v0 = *(const float4*)ap;
            float4 v1 = *(const float4*)(ap + 4);
            float vv[8] = {v0.x,v0.y,v0.z,v0.w,v1.x,v1.y,v1.z,v1.w};
            s8v hv, lv;
            #pragma unroll
            for (int j=0;j<8;++j){
                u16 hi = f2b(vv[j]);
                hv[j] = (short)hi;
                if (SPLITA) lv[j] = (short)f2b(vv[j] - b2f(hi));
            }
            int fb = ((w<<1)+kf)<<9;
            *(s8v*)&Ash[fb + lo8] = hv;
            if (SPLITA) *(s8v*)&Asl[fb + lo8] = lv;
            size_t gb = (size_t)(bn + (w<<5) + l31) * K + kk;
            gl_lds16(Wh + gb, &Bsh[fb]);
            if (SPLITA) gl_lds16(Wl + gb, &Bsl[fb]);
        }
        __syncthreads();
        #pragma unroll
        for (int kf = 0; kf < 2; ++kf){
            s8v ah[2], al[2];
            #pragma unroll
            for (int rti=0;rti<2;++rti){
                int fa = (((((wr<<1)+rti)<<1)+kf)<<9) + lo8;
                ah[rti] = *(const s8v*)&Ash[fa];
                if (SPLITA) al[rti] = *(const s8v*)&Asl[fa];
            }
            #pragma unroll
            for (int cti=0;cti<2;++cti){
                int fb = (((((wc<<1)+cti)<<1)+kf)<<9) + lo8;
                s8v bh = *(const s8v*)&Bsh[fb];
                s8v bl;
                if (SPLITA) bl = *(const s8v*)&Bsl[fb];
                #pragma unroll
                for (int rti=0;rti<2;++rti){
                    acc[rti][cti] = MFMA32(ah[rti], bh, acc[rti][cti]);
                    if (SPLITA){
                        acc[rti][cti] = MFMA32(ah[rti], bl, acc[rti][cti]);
                        acc[rti][cti] = MFMA32(al[rti], bh, acc[rti][cti]);
                    }
                }
            }
        }
    }
    // epilogue: C layout col=l31, row = 8g + 4*l5 + i
    #pragma unroll
    for (int cti=0;cti<2;++cti){
        int col = bn + (((wc<<1)+cti)<<5) + l31;
        float bv = bias[col];
        #pragma unroll
        for (int rti=0;rti<2;++rti){
            int rbase = bm + (((wr<<1)+rti)<<5) + (l5<<2);
            #pragma unroll
            for (int g=0;g<4;++g){
                #pragma unroll
                for (int i=0;i<4;++i){
                    int row = rbase + (g<<3) + i;
                    float v = acc[rti][cti][(g<<2)+i] + bv;
                    if (OUTMODE==0){
                        Cf[(size_t)row*N + col] = leakyf(v);
                    } else {
                        u16 hi = f2b(v);
                        Ch[(size_t)row*N + col] = hi;
                        Cl[(size_t)row*N + col] = f2b(v - b2f(hi));
                    }
                }
            }
        }
    }
}

// ---------------- fused dual MFMA GEMM for lin12 ----------------
__global__ __launch_bounds__(256,2) void lin12_mfma(
    const u16* __restrict__ EHH, const u16* __restrict__ EHL, const u16* __restrict__ ENH,
    const u16* __restrict__ W1b, const float* __restrict__ B1,
    const u16* __restrict__ W2b, const float* __restrict__ B2,
    float* __restrict__ OUT)
{
    const int K = 512, N = 512;
    __shared__ u16 Ss[4096], Ms[4096], B1s[4096], B2s[4096];
    int tid = threadIdx.x, w = tid >> 6, lane = tid & 63;
    int l31 = lane & 31, l5 = lane >> 5, lo8 = lane << 3;
    int wr = w >> 1, wc = w & 1;
    int bm = blockIdx.x << 7, bn = blockIdx.y << 7;

    f16f acc1[2][2], acc2[2][2];
    #pragma unroll
    for (int a0=0;a0<2;++a0)
        #pragma unroll
        for (int a1=0;a1<2;++a1)
            #pragma unroll
            for (int e=0;e<16;++e){ acc1[a0][a1][e]=0.f; acc2[a0][a1][e]=0.f; }

    for (int k0 = 0; k0 < K; k0 += 32){
        __syncthreads();
        #pragma unroll
        for (int kf = 0; kf < 2; ++kf){
            int kk = k0 + (kf<<4) + (l5<<3);
            size_t go = (size_t)(bm + (w<<5) + l31) * K + kk;
            s8v hv = *(const s8v*)(EHH + go);
            s8v lv = *(const s8v*)(EHL + go);
            s8v nv = *(const s8v*)(ENH + go);
            s8v sv, mv;
            #pragma unroll
            for (int j=0;j<8;++j){
                float e = b2f((u16)hv[j]) + b2f((u16)lv[j]);
                float n = b2f((u16)nv[j]);
                sv[j] = (short)f2b(e + n);
                mv[j] = (short)f2b(e * n);
            }
            int fb = ((w<<1)+kf)<<9;
            *(s8v*)&Ss[fb + lo8] = sv;
            *(s8v*)&Ms[fb + lo8] = mv;
            size_t gb = (size_t)(bn + (w<<5) + l31) * K + kk;
            gl_lds16(W1b + gb, &B1s[fb]);
            gl_lds16(W2b + gb, &B2s[fb]);
        }
        __syncthreads();
        #pragma unroll
        for (int kf = 0; kf < 2; ++kf){
            s8v as[2], am[2];
            #pragma unroll
            for (int rti=0;rti<2;++rti){
                int fa = (((((wr<<1)+rti)<<1)+kf)<<9) + lo8;
                as[rti] = *(const s8v*)&Ss[fa];
                am[rti] = *(const s8v*)&Ms[fa];
            }
            #pragma unroll
            for (int cti=0;cti<2;++cti){
                int fb = (((((wc<<1)+cti)<<1)+kf)<<9) + lo8;
                s8v b1 = *(const s8v*)&B1s[fb];
                s8v b2 = *(const s8v*)&B2s[fb];
                #pragma unroll
                for (int rti=0;rti<2;++rti){
                    acc1[rti][cti] = MFMA32(as[rti], b1, acc1[rti][cti]);
                    acc2[rti][cti] = MFMA32(am[rti], b2, acc2[rti][cti]);
                }
            }
        }
    }
    #pragma unroll
    for (int cti=0;cti<2;++cti){
        int col = bn + (((wc<<1)+cti)<<5) + l31;
        float b1v = B1[col], b2v = B2[col];
        #pragma unroll
        for (int rti=0;rti<2;++rti){
            int rbase = bm + (((wr<<1)+rti)<<5) + (l5<<2);
            #pragma unroll
            for (int g=0;g<4;++g){
                #pragma unroll
                for (int i=0;i<4;++i){
                    int row = rbase + (g<<3) + i;
                    float s1 = leakyf(acc1[rti][cti][(g<<2)+i] + b1v);
                    float s2 = leakyf(acc2[rti][cti][(g<<2)+i] + b2v);
                    OUT[(size_t)row*N + col] = s1 + s2;
                }
            }
        }
    }
}

// ---------------- column mean + h update (VALIDATED — summation order is load-bearing,
// the top-6 selection is sensitive to the exact fp32 mean; NEVER change this kernel) ----------------
__global__ __launch_bounds__(256) void colmean(const float* __restrict__ H, float* __restrict__ Mc)
{
    __shared__ float red[256];
    int c=blockIdx.x, t=threadIdx.x;
    float s=0;
    for (int i=t;i<8192;i+=256) s += H[(size_t)i*512 + c];
    red[t]=s; __syncthreads();
    for (int o=128;o>0;o>>=1){ if(t<o) red[t]+=red[t+o]; __syncthreads(); }
    if (t==0) Mc[c] = red[0] * (1.0f/8192.0f);
}

__global__ __launch_bounds__(256) void hupd(float* __restrict__ H, const float* __restrict__ Mc)
{
    int i = blockIdx.x*256 + threadIdx.x;
    H[i] = (H[i] + Mc[i & 511]) * 0.5f;
}

// ---------------- logits: split-bf16 MFMA + fused top-6, 64x128 wave tile (R12-validated) ----------------
// Grid (64,8). Block 128 rows x 1024 cols (4 bn-tiles of 256). Wave tile 64x128.
struct TileMem { u16 Ah[4096]; u16 Al[4096]; u16 Bh[8192]; u16 Bl[8192]; }; // 49152 B
struct EpiMem  { float Sc[64*132]; };                                       // 33792 B
union SMemU { TileMem t; EpiMem e; };

__global__ __launch_bounds__(256,2) void logits_topk_mfma(
    const u16* __restrict__ EHH, const u16* __restrict__ EHL,
    const u16* __restrict__ ETH, const u16* __restrict__ ETL,
    float* __restrict__ VALS, int* __restrict__ IDX)
{
    const float scale = 0.04419417382415922f; // 512^-0.5
    __shared__ SMemU sm;
    int tid = threadIdx.x;
    int bm = blockIdx.x << 7;
    int base = blockIdx.y << 10;
    int w = tid >> 6, lane = tid & 63;
    int l31 = lane & 31, l5 = lane >> 5, lo8 = lane << 3;
    int wr = w >> 1, wc = w & 1;
    int r = tid >> 1, q = tid & 1;

    float tv[6]; int ti[6];
    #pragma unroll
    for (int k=0;k<6;++k){ tv[k]=-INFINITY; ti[k]=0; }

    for (int bt = 0; bt < 4; ++bt){
        int bn = base + (bt<<8);
        f16f acc[2][4];
        #pragma unroll
        for (int a0=0;a0<2;++a0)
            #pragma unroll
            for (int a1=0;a1<4;++a1)
                #pragma unroll
                for (int e=0;e<16;++e) acc[a0][a1][e] = 0.f;

        for (int k0 = 0; k0 < 512; k0 += 32){
            __syncthreads();
            #pragma unroll
            for (int kf = 0; kf < 2; ++kf){
                int kk = k0 + (kf<<4) + (l5<<3);
                size_t ga = (size_t)(bm + (w<<5) + l31) * 512 + kk;
                gl_lds16(EHH + ga, &sm.t.Ah[((w<<1)+kf)<<9]);
                gl_lds16(EHL + ga, &sm.t.Al[((w<<1)+kf)<<9]);
                #pragma unroll
                for (int j = 0; j < 2; ++j){
                    int ct = (w<<1) + j;
                    size_t gb = (size_t)(bn + (ct<<5) + l31) * 512 + kk;
                    gl_lds16(ETH + gb, &sm.t.Bh[((ct<<1)+kf)<<9]);
                    gl_lds16(ETL + gb, &sm.t.Bl[((ct<<1)+kf)<<9]);
                }
            }
            __syncthreads();
            #pragma unroll
            for (int kf = 0; kf < 2; ++kf){
                s8v ah[2], al[2];
                #pragma unroll
                for (int rti=0;rti<2;++rti){
                    int fa = (((((wr<<1)+rti)<<1)+kf)<<9) + lo8;
                    ah[rti] = *(const s8v*)&sm.t.Ah[fa];
                    al[rti] = *(const s8v*)&sm.t.Al[fa];
                }
                #pragma unroll
                for (int cti=0;cti<4;++cti){
                    int fb = (((((wc<<2)+cti)<<1)+kf)<<9) + lo8;
                    s8v bh = *(const s8v*)&sm.t.Bh[fb];
                    s8v bl = *(const s8v*)&sm.t.Bl[fb];
                    #pragma unroll
                    for (int rti=0;rti<2;++rti){
                        acc[rti][cti] = MFMA32(ah[rti], bh, acc[rti][cti]);
                        acc[rti][cti] = MFMA32(ah[rti], bl, acc[rti][cti]);
                        acc[rti][cti] = MFMA32(al[rti], bh, acc[rti][cti]);
                    }
                }
            }
        }
        __syncthreads();
        // epilogue: 4 sub-halves of 64 cols; Sc column-major [64][132]
        #pragma unroll
        for (int s = 0; s < 4; ++s){
            if (wc == (s>>1)){
                #pragma unroll
                for (int cp=0;cp<2;++cp){
                    int cti = ((s&1)<<1) + cp;
                    int colw = ((cp<<5) + l31) * 132 + (wr<<6) + (l5<<2);
                    #pragma unroll
                    for (int rti=0;rti<2;++rti){
                        #pragma unroll
                        for (int g=0;g<4;++g){
                            float4 vv;
                            vv.x = acc[rti][cti][(g<<2)+0]*scale;
                            vv.y = acc[rti][cti][(g<<2)+1]*scale;
                            vv.z = acc[rti][cti][(g<<2)+2]*scale;
                            vv.w = acc[rti][cti][(g<<2)+3]*scale;
                            *(float4*)&sm.e.Sc[colw + (rti<<5) + (g<<3)] = vv;
                        }
                    }
                }
            }
            __syncthreads();
            int cbase = bn + (s<<6) + (q<<5);
            #pragma unroll
            for (int i=0;i<32;++i){
                float v = sm.e.Sc[(((q<<5)+i)*132) + r];
                if (v > tv[5]){
                    tv[5]=v; ti[5]=cbase+i;
                    #pragma unroll
                    for (int u=5;u>0;--u){
                        if (tv[u] > tv[u-1]){
                            float tf=tv[u]; tv[u]=tv[u-1]; tv[u-1]=tf;
                            int tg=ti[u]; ti[u]=ti[u-1]; ti[u-1]=tg;
                        }
                    }
                }
            }
            __syncthreads();
        }
    }
    // merge q halves -> per-block top6
    float* Mv = sm.e.Sc;
    int*   Mi = (int*)sm.e.Sc + 1536;
    #pragma unroll
    for (int k=0;k<6;++k){ Mv[r*12 + q*6 + k] = tv[k]; Mi[r*12 + q*6 + k] = ti[k]; }
    __syncthreads();
    if (tid < 128){
        int row = bm + tid;
        float* mv = &Mv[tid*12];
        int*   mi = &Mi[tid*12];
        unsigned used = 0;
        for (int k=0;k<6;++k){
            float bv=-INFINITY; int bc=0;
            for (int c=0;c<12;++c) if (!((used>>c)&1u) && mv[c] > bv){ bv=mv[c]; bc=c; }
            used |= 1u<<bc;
            VALS[(size_t)row*48 + blockIdx.y*6 + k] = bv;
            IDX [(size_t)row*48 + blockIdx.y*6 + k] = mi[bc];
        }
    }
}

// ---------------- KNN aggregation: 48-entry butterfly merge (R12-validated) ----------------
__global__ __launch_bounds__(256) void knn_agg(
    const u16* __restrict__ EHH, const u16* __restrict__ EHL,
    const u16* __restrict__ ETH, const u16* __restrict__ ETL,
    const float* __restrict__ VALS, const int* __restrict__ IDX,
    u16* __restrict__ ENH)
{
    int wave = threadIdx.x >> 6, lane = threadIdx.x & 63;
    int row = (blockIdx.x<<2) + wave;
    size_t vb = (size_t)row*48;
    float v0 = (lane < 48) ? VALS[vb + lane] : -INFINITY;
    int e0 = lane;
    float v[6]; int id[6];
    #pragma unroll
    for (int k=0;k<6;++k){
        float cv = v0; int ce = e0;
        #pragma unroll
        for (int off=1; off<64; off<<=1){
            float ov = __shfl_xor(cv, off, 64);
            int   oe = __shfl_xor(ce, off, 64);
            if (ov > cv || (ov == cv && oe < ce)){ cv=ov; ce=oe; }
        }
        v[k] = cv;
        id[k] = IDX[vb + ce];
        if (e0 == ce) v0 = -INFINITY;
    }
    float mx=v[0];
    #pragma unroll
    for (int k=1;k<6;++k) mx=fmaxf(mx,v[k]);
    float p[6], se=0.f;
    #pragma unroll
    for (int k=0;k<6;++k){ p[k]=expf(v[k]-mx); se+=p[k]; }
    float inv=1.f/se;
    #pragma unroll
    for (int k=0;k<6;++k) p[k]*=inv;

    size_t ro = (size_t)row*512;
    float e[8];
    #pragma unroll
    for (int j=0;j<8;++j){ int o = lane + (j<<6); e[j]=b2f(EHH[ro+o])+b2f(EHL[ro+o]); }
    float nb[6][8], sn[6], sg[6];
    #pragma unroll
    for (int k=0;k<6;++k){
        size_t no = (size_t)id[k]*512;
        float s_n=0.f, s_g=0.f;
        #pragma unroll
        for (int j=0;j<8;++j){
            int o = lane + (j<<6);
            float nv = b2f(ETH[no+o])+b2f(ETL[no+o]);
            nb[k][j]=nv;
            s_n += nv;
            float ehr_v = p[k]*nv + (1.f-p[k])*e[j];
            s_g += tanhf(e[j] + ehr_v);
        }
        #pragma unroll
        for (int o=1;o<64;o<<=1){ s_n += __shfl_xor(s_n,o,64); s_g += __shfl_xor(s_g,o,64); }
        sn[k]=s_n; sg[k]=s_g;
    }
    float ka[6];
    #pragma unroll
    for (int k=0;k<6;++k) ka[k]=sn[k]*sg[k];
    float km=ka[0];
    #pragma unroll
    for (int k=1;k<6;++k) km=fmaxf(km,ka[k]);
    float kp[6], ks=0.f;
    #pragma unroll
    for (int k=0;k<6;++k){ kp[k]=expf(ka[k]-km); ks+=kp[k]; }
    float kinv=1.f/ks;
    #pragma unroll
    for (int k=0;k<6;++k) kp[k]*=kinv;
    float o8[8]={0,0,0,0,0,0,0,0};
    #pragma unroll
    for (int k=0;k<6;++k)
        #pragma unroll
        for (int j=0;j<8;++j) o8[j] += kp[k]*nb[k][j];
    #pragma unroll
    for (int j=0;j<8;++j) ENH[ro + lane + (j<<6)] = f2b(o8[j]);
}

// ---------------- attention readout ----------------
__global__ __launch_bounds__(256) void att_g(
    const float* __restrict__ HM, const float* __restrict__ W2,
    const float* __restrict__ B2, float* __restrict__ G)
{
    int wave=threadIdx.x>>6, lane=threadIdx.x&63;
    int row=(blockIdx.x<<2)+wave;
    const float* hr = HM + (size_t)row*256;
    float s=0.f;
    #pragma unroll
    for (int j=0;j<4;++j) s += hr[lane+(j<<6)] * W2[lane+(j<<6)];
    #pragma unroll
    for (int o=1;o<64;o<<=1) s += __shfl_xor(s,o,64);
    if (lane==0) G[row] = s + B2[0];
}

__global__ __launch_bounds__(1024) void softg(float* __restrict__ G, float* __restrict__ EGP)
{
    __shared__ float red[1024];
    __shared__ float MS[2];
    int t=threadIdx.x;
    if (t < 512) EGP[t] = 0.f;   // zero e_g accumulator for eg_at atomics
    float m=-INFINITY;
    for (int i=t;i<8192;i+=1024) m=fmaxf(m,G[i]);
    red[t]=m; __syncthreads();
    for (int o=512;o>0;o>>=1){ if(t<o) red[t]=fmaxf(red[t],red[t+o]); __syncthreads(); }
    if (t==0) MS[0]=red[0];
    __syncthreads();
    float M=MS[0], s=0.f;
    for (int i=t;i<8192;i+=1024) s += expf(G[i]-M);
    red[t]=s; __syncthreads();
    for (int o=512;o>0;o>>=1){ if(t<o) red[t]+=red[t+o]; __syncthreads(); }
    if (t==0) MS[1]=red[0];
    __syncthreads();
    float inv=1.f/MS[1];
    for (int i=t;i<8192;i+=1024) G[i] = expf(G[i]-M)*inv;
}

// coalesced e_g: row-panel partials + atomics (EGP pre-zeroed by softg)
__global__ __launch_bounds__(256) void eg_at(
    const float* __restrict__ A, const float* __restrict__ X, float* __restrict__ OUT)
{
    int b = blockIdx.x, t = threadIdx.x;
    float s0=0.f, s1=0.f;
    for (int r=0;r<64;++r){
        int row = b*64 + r;
        float a = A[row];
        const float* xr = X + (size_t)row*512;
        s0 += a * xr[t];
        s1 += a * xr[t+256];
    }
    atomicAdd(&OUT[t], s0);
    atomicAdd(&OUT[t+256], s1);
}

// ---------------- launch ----------------
extern "C" void kernel_launch(void* const* d_in, const int* in_sizes, int n_in,
                              void* d_out, int out_size, void* d_ws, size_t ws_size,
                              hipStream_t stream)
{
    (void)n_in; (void)out_size; (void)ws_size;
    static const int ss[6] = {89,334,534,471,1510,482};

    bool sig_order = (in_sizes[12] == 1536);
    OmicArgs oa;
    const float *sb1, *sw2, *sb2, *xpath;
    if (sig_order) {
        for (int i=0;i<6;++i){ oa.x[i]=(const float*)d_in[i]; oa.w1[i]=(const float*)d_in[6+i]; oa.s[i]=ss[i]; }
        sb1   = (const float*)d_in[12];
        sw2   = (const float*)d_in[13];
        sb2   = (const float*)d_in[14];
        xpath = (const float*)d_in[15];
    } else {
        for (int i=0;i<6;++i){ oa.x[i]=(const float*)d_in[2*i]; oa.w1[i]=(const float*)d_in[2*i+1]; oa.s[i]=ss[i]; }
        xpath = (const float*)d_in[12];
        sb1   = (const float*)d_in[13];
        sw2   = (const float*)d_in[14];
        sb2   = (const float*)d_in[15];
    }
    const float* fc1w = (const float*)d_in[16];
    const float* fc1b = (const float*)d_in[17];
    const float* whw  = (const float*)d_in[18];
    const float* whb  = (const float*)d_in[19];
    const float* wtw  = (const float*)d_in[20];
    const float* wtb  = (const float*)d_in[21];
    const float* l1w  = (const float*)d_in[22];
    const float* l1b  = (const float*)d_in[23];
    const float* l2w  = (const float*)d_in[24];
    const float* l2b  = (const float*)d_in[25];
    const float* aw1  = (const float*)d_in[26];
    const float* ab1  = (const float*)d_in[27];
    const float* aw2  = (const float*)d_in[28];
    const float* ab2  = (const float*)d_in[29];

    float* out = (float*)d_out;            // fp32: e_omic(1536) | e_h2(8192*512) | e_g(512)
    float* eh2 = out + 1536;
    float* egp = out + 1536 + 4194304;

    // Lifetimes in the e_h2 output region: h fp32 [fc1 .. wh/wt], then vals/idx
    // [logits .. knn] (R12-validated offsets, 48/row), then final e_h2 [lin12 ..].
    float* h    = eh2;
    float* vals = eh2;                     // 8192*48 floats
    int*   idxb = (int*)(eh2 + 786432);    // 8192*48 ints

    char* wsb = (char*)d_ws;
    u16* ehh = (u16*)wsb;                               // 8 MB
    u16* ehl = ehh + 4194304;                           // 8 MB
    u16* eth = ehl + 4194304;                           // 8 MB (later hm fp32)
    u16* etl = eth + 4194304;                           // 8 MB
    u16* enh = etl + 4194304;                           // 8 MB (bf16)
    u16* wreg = enh + 4194304;                          // 4 MB weight splits
    u16* fc1h = wreg,            *fc1l = wreg +  196608;
    u16* whh  = wreg +  393216,  *whl  = wreg +  655360;
    u16* wth  = wreg +  917504,  *wtl  = wreg + 1179648;
    u16* l1bf = wreg + 1441792,  *l2bf = wreg + 1703936;
    u16* awbf = wreg + 1966080;                         // ends at wreg+2097152
    float* mcol = (float*)(wsb + 48234496);             // 512 (R12-validated offset)
    float* gbuf = mcol + 512;                           // 8192
    float* hm   = (float*)eth;

    omic_kernel<<<6,256,0,stream>>>(oa, sb1, sw2, sb2, out);

    WcArgs wa;
    wa.seg[0] = { fc1w, fc1h, fc1l, 196608 };
    wa.seg[1] = { whw,  whh,  whl,  262144 };
    wa.seg[2] = { wtw,  wth,  wtl,  262144 };
    wa.seg[3] = { l1w,  l1bf, nullptr, 262144 };
    wa.seg[4] = { l2w,  l2bf, nullptr, 262144 };
    wa.seg[5] = { aw1,  awbf, nullptr, 131072 };
    wconv<<<dim3(16,6),256,0,stream>>>(wa);

    gemm_mfma<1,0><<<dim3(64,4),256,0,stream>>>(xpath, fc1h, fc1l, fc1b,
        h, nullptr, nullptr, 8192,512,384);
    colmean<<<512,256,0,stream>>>(h, mcol);
    hupd<<<16384,256,0,stream>>>(h, mcol);
    gemm_mfma<1,1><<<dim3(64,4),256,0,stream>>>(h, whh, whl, whb,
        nullptr, ehh, ehl, 8192,512,512);
    gemm_mfma<1,1><<<dim3(64,4),256,0,stream>>>(h, wth, wtl, wtb,
        nullptr, eth, etl, 8192,512,512);
    logits_topk_mfma<<<dim3(64,8),256,0,stream>>>(ehh, ehl, eth, etl, vals, idxb);
    knn_agg<<<2048,256,0,stream>>>(ehh, ehl, eth, etl, vals, idxb, enh);
    lin12_mfma<<<dim3(64,4),256,0,stream>>>(ehh, ehl, enh, l1bf, l1b, l2bf, l2b, eh2);
    gemm_mfma<0,0><<<dim3(64,2),256,0,stream>>>(eh2, awbf, awbf, ab1,
        hm, nullptr, nullptr, 8192,256,512);
    att_g<<<2048,256,0,stream>>>(hm, aw2, ab2, gbuf);
    softg<<<1,1024,0,stream>>>(gbuf, egp);
    eg_at<<<128,256,0,stream>>>(gbuf, eh2, egp);
}

// Round 16
// 806.956 us; speedup vs baseline: 1.6079x; 1.6079x over previous
//
#include <hip/hip_runtime.h>
#include <math.h>

typedef unsigned short u16;
typedef unsigned int u32;
typedef __attribute__((ext_vector_type(8))) short s8v;    // 8 x bf16 (4 VGPRs)
typedef __attribute__((ext_vector_type(16))) float f16f;  // 32x32 MFMA acc

__device__ __forceinline__ float b2f(u16 u){ union{u32 i; float f;} v; v.i=((u32)u)<<16; return v.f; }
__device__ __forceinline__ u16 f2b(float f){ union{float f; u32 i;} v; v.f=f; u32 x=v.i; return (u16)((x + 0x7fffu + ((x>>16)&1u)) >> 16); }
__device__ __forceinline__ float leakyf(float x){ return x>=0.f? x : 0.01f*x; }

#define MFMA32(a,b,c) __builtin_amdgcn_mfma_f32_32x32x16_bf16(a,b,c,0,0,0)

// async global->LDS, 16B per lane, dest = wave-uniform base + lane*16
__device__ __forceinline__ void gl_lds16(const void* g, void* l){
    __builtin_amdgcn_global_load_lds(
        (const __attribute__((address_space(1))) u32*)g,
        (__attribute__((address_space(3))) u32*)l, 16, 0, 0);
}

// ---------------- omic SNN branches (R12-validated per-thread form) ----------------
struct OmicArgs {
    const float* x[6];
    const float* w1[6];
    int s[6];
};

__global__ __launch_bounds__(256) void omic_kernel(OmicArgs oa,
        const float* __restrict__ sb1, const float* __restrict__ sw2,
        const float* __restrict__ sb2, float* __restrict__ out)
{
    int br = blockIdx.x;
    int t = threadIdx.x;
    int s = oa.s[br];
    __shared__ float xs[1536];
    __shared__ float h1[256];
    const float* x = oa.x[br];
    for (int i=t;i<s;i+=256) xs[i] = x[i];
    __syncthreads();
    const float* w1r = oa.w1[br] + (size_t)t * s;
    float a = sb1[br*256+t];
    for (int i=0;i<s;++i) a += xs[i]*w1r[i];
    a = a>0.f ? a : expm1f(a);
    h1[t] = a;
    __syncthreads();
    const float* w2r = sw2 + (size_t)br*65536 + (size_t)t*256;
    float a2 = sb2[br*256+t];
    #pragma unroll 4
    for (int i=0;i<256;++i) a2 += h1[i]*w2r[i];
    a2 = a2>0.f ? a2 : expm1f(a2);
    out[br*256+t] = a2;
}

// ---------------- batched weight conversion fp32 -> bf16 hi (+lo) ----------------
struct WcSeg { const float* s; u16* dh; u16* dl; int n; };
struct WcArgs { WcSeg seg[6]; };

__global__ __launch_bounds__(256) void wconv(WcArgs a)
{
    WcSeg sg = a.seg[blockIdx.y];
    for (int i = blockIdx.x*256 + threadIdx.x; i < sg.n; i += gridDim.x*256){
        float v = sg.s[i];
        u16 hi = f2b(v);
        sg.dh[i] = hi;
        if (sg.dl) sg.dl[i] = f2b(v - b2f(hi));
    }
}

// ---------------- general MFMA GEMM: C = act(A[M,K]fp32 * W[N,K]^T + b) ----------------
// Block 128x128, 4 waves of 64x64 (2x2 32x32 MFMA tiles). K-chunk 32.
// OUTMODE 0: fp32 out + leaky.  OUTMODE 1: split u16 hi/lo out, no act.
template<int SPLITA, int OUTMODE>
__global__ __launch_bounds__(256,2) void gemm_mfma(
    const float* __restrict__ A, const u16* __restrict__ Wh, const u16* __restrict__ Wl,
    const float* __restrict__ bias,
    float* __restrict__ Cf, u16* __restrict__ Ch, u16* __restrict__ Cl,
    int M, int N, int K)
{
    __shared__ u16 Ash[4096], Asl[4096], Bsh[4096], Bsl[4096];
    int tid = threadIdx.x, w = tid >> 6, lane = tid & 63;
    int l31 = lane & 31, l5 = lane >> 5, lo8 = lane << 3;
    int wr = w >> 1, wc = w & 1;
    int bm = blockIdx.x << 7, bn = blockIdx.y << 7;

    f16f acc[2][2];
    #pragma unroll
    for (int a0=0;a0<2;++a0)
        #pragma unroll
        for (int a1=0;a1<2;++a1)
            #pragma unroll
            for (int e=0;e<16;++e) acc[a0][a1][e] = 0.f;

    for (int k0 = 0; k0 < K; k0 += 32){
        __syncthreads();
        #pragma unroll
        for (int kf = 0; kf < 2; ++kf){
            int kk = k0 + (kf<<4) + (l5<<3);
            const float* ap = A + (size_t)(bm + (w<<5) + l31) * K + kk;
            float4 v0 = *(const float4*)ap;
            float4 v1 = *(const float4*)(ap + 4);
            float vv[8] = {v0.x,v0.y,v0.z,v0.w,v1.x,v1.y,v1.z,v1.w};
            s8v hv, lv;
            #pragma unroll
            for (int j=0;j<8;++j){
                u16 hi = f2b(vv[j]);
                hv[j] = (short)hi;
                if (SPLITA) lv[j] = (short)f2b(vv[j] - b2f(hi));
            }
            int fb = ((w<<1)+kf)<<9;
            *(s8v*)&Ash[fb + lo8] = hv;
            if (SPLITA) *(s8v*)&Asl[fb + lo8] = lv;
            size_t gb = (size_t)(bn + (w<<5) + l31) * K + kk;
            gl_lds16(Wh + gb, &Bsh[fb]);
            if (SPLITA) gl_lds16(Wl + gb, &Bsl[fb]);
        }
        __syncthreads();
        #pragma unroll
        for (int kf = 0; kf < 2; ++kf){
            s8v ah[2], al[2];
            #pragma unroll
            for (int rti=0;rti<2;++rti){
                int fa = (((((wr<<1)+rti)<<1)+kf)<<9) + lo8;
                ah[rti] = *(const s8v*)&Ash[fa];
                if (SPLITA) al[rti] = *(const s8v*)&Asl[fa];
            }
            #pragma unroll
            for (int cti=0;cti<2;++cti){
                int fb = (((((wc<<1)+cti)<<1)+kf)<<9) + lo8;
                s8v bh = *(const s8v*)&Bsh[fb];
                s8v bl;
                if (SPLITA) bl = *(const s8v*)&Bsl[fb];
                #pragma unroll
                for (int rti=0;rti<2;++rti){
                    acc[rti][cti] = MFMA32(ah[rti], bh, acc[rti][cti]);
                    if (SPLITA){
                        acc[rti][cti] = MFMA32(ah[rti], bl, acc[rti][cti]);
                        acc[rti][cti] = MFMA32(al[rti], bh, acc[rti][cti]);
                    }
                }
            }
        }
    }
    // epilogue: C layout col=l31, row = 8g + 4*l5 + i
    #pragma unroll
    for (int cti=0;cti<2;++cti){
        int col = bn + (((wc<<1)+cti)<<5) + l31;
        float bv = bias[col];
        #pragma unroll
        for (int rti=0;rti<2;++rti){
            int rbase = bm + (((wr<<1)+rti)<<5) + (l5<<2);
            #pragma unroll
            for (int g=0;g<4;++g){
                #pragma unroll
                for (int i=0;i<4;++i){
                    int row = rbase + (g<<3) + i;
                    float v = acc[rti][cti][(g<<2)+i] + bv;
                    if (OUTMODE==0){
                        Cf[(size_t)row*N + col] = leakyf(v);
                    } else {
                        u16 hi = f2b(v);
                        Ch[(size_t)row*N + col] = hi;
                        Cl[(size_t)row*N + col] = f2b(v - b2f(hi));
                    }
                }
            }
        }
    }
}

// ---------------- fused dual MFMA GEMM for lin12 ----------------
__global__ __launch_bounds__(256,2) void lin12_mfma(
    const u16* __restrict__ EHH, const u16* __restrict__ EHL, const u16* __restrict__ ENH,
    const u16* __restrict__ W1b, const float* __restrict__ B1,
    const u16* __restrict__ W2b, const float* __restrict__ B2,
    float* __restrict__ OUT)
{
    const int K = 512, N = 512;
    __shared__ u16 Ss[4096], Ms[4096], B1s[4096], B2s[4096];
    int tid = threadIdx.x, w = tid >> 6, lane = tid & 63;
    int l31 = lane & 31, l5 = lane >> 5, lo8 = lane << 3;
    int wr = w >> 1, wc = w & 1;
    int bm = blockIdx.x << 7, bn = blockIdx.y << 7;

    f16f acc1[2][2], acc2[2][2];
    #pragma unroll
    for (int a0=0;a0<2;++a0)
        #pragma unroll
        for (int a1=0;a1<2;++a1)
            #pragma unroll
            for (int e=0;e<16;++e){ acc1[a0][a1][e]=0.f; acc2[a0][a1][e]=0.f; }

    for (int k0 = 0; k0 < K; k0 += 32){
        __syncthreads();
        #pragma unroll
        for (int kf = 0; kf < 2; ++kf){
            int kk = k0 + (kf<<4) + (l5<<3);
            size_t go = (size_t)(bm + (w<<5) + l31) * K + kk;
            s8v hv = *(const s8v*)(EHH + go);
            s8v lv = *(const s8v*)(EHL + go);
            s8v nv = *(const s8v*)(ENH + go);
            s8v sv, mv;
            #pragma unroll
            for (int j=0;j<8;++j){
                float e = b2f((u16)hv[j]) + b2f((u16)lv[j]);
                float n = b2f((u16)nv[j]);
                sv[j] = (short)f2b(e + n);
                mv[j] = (short)f2b(e * n);
            }
            int fb = ((w<<1)+kf)<<9;
            *(s8v*)&Ss[fb + lo8] = sv;
            *(s8v*)&Ms[fb + lo8] = mv;
            size_t gb = (size_t)(bn + (w<<5) + l31) * K + kk;
            gl_lds16(W1b + gb, &B1s[fb]);
            gl_lds16(W2b + gb, &B2s[fb]);
        }
        __syncthreads();
        #pragma unroll
        for (int kf = 0; kf < 2; ++kf){
            s8v as[2], am[2];
            #pragma unroll
            for (int rti=0;rti<2;++rti){
                int fa = (((((wr<<1)+rti)<<1)+kf)<<9) + lo8;
                as[rti] = *(const s8v*)&Ss[fa];
                am[rti] = *(const s8v*)&Ms[fa];
            }
            #pragma unroll
            for (int cti=0;cti<2;++cti){
                int fb = (((((wc<<1)+cti)<<1)+kf)<<9) + lo8;
                s8v b1 = *(const s8v*)&B1s[fb];
                s8v b2 = *(const s8v*)&B2s[fb];
                #pragma unroll
                for (int rti=0;rti<2;++rti){
                    acc1[rti][cti] = MFMA32(as[rti], b1, acc1[rti][cti]);
                    acc2[rti][cti] = MFMA32(am[rti], b2, acc2[rti][cti]);
                }
            }
        }
    }
    #pragma unroll
    for (int cti=0;cti<2;++cti){
        int col = bn + (((wc<<1)+cti)<<5) + l31;
        float b1v = B1[col], b2v = B2[col];
        #pragma unroll
        for (int rti=0;rti<2;++rti){
            int rbase = bm + (((wr<<1)+rti)<<5) + (l5<<2);
            #pragma unroll
            for (int g=0;g<4;++g){
                #pragma unroll
                for (int i=0;i<4;++i){
                    int row = rbase + (g<<3) + i;
                    float s1 = leakyf(acc1[rti][cti][(g<<2)+i] + b1v);
                    float s2 = leakyf(acc2[rti][cti][(g<<2)+i] + b2v);
                    OUT[(size_t)row*N + col] = s1 + s2;
                }
            }
        }
    }
}

// ---------------- column mean + h update (VALIDATED — summation order is load-bearing,
// the top-6 selection is sensitive to the exact fp32 mean; NEVER change this kernel) ----------------
__global__ __launch_bounds__(256) void colmean(const float* __restrict__ H, float* __restrict__ Mc)
{
    __shared__ float red[256];
    int c=blockIdx.x, t=threadIdx.x;
    float s=0;
    for (int i=t;i<8192;i+=256) s += H[(size_t)i*512 + c];
    red[t]=s; __syncthreads();
    for (int o=128;o>0;o>>=1){ if(t<o) red[t]+=red[t+o]; __syncthreads(); }
    if (t==0) Mc[c] = red[0] * (1.0f/8192.0f);
}

__global__ __launch_bounds__(256) void hupd(float* __restrict__ H, const float* __restrict__ Mc)
{
    int i = blockIdx.x*256 + threadIdx.x;
    H[i] = (H[i] + Mc[i & 511]) * 0.5f;
}

// ---------------- logits: split-bf16 MFMA + fused top-6, 64x128 wave tile (R12-validated) ----------------
// Grid (64,8). Block 128 rows x 1024 cols (4 bn-tiles of 256). Wave tile 64x128.
struct TileMem { u16 Ah[4096]; u16 Al[4096]; u16 Bh[8192]; u16 Bl[8192]; }; // 49152 B
struct EpiMem  { float Sc[64*132]; };                                       // 33792 B
union SMemU { TileMem t; EpiMem e; };

__global__ __launch_bounds__(256,2) void logits_topk_mfma(
    const u16* __restrict__ EHH, const u16* __restrict__ EHL,
    const u16* __restrict__ ETH, const u16* __restrict__ ETL,
    float* __restrict__ VALS, int* __restrict__ IDX)
{
    const float scale = 0.04419417382415922f; // 512^-0.5
    __shared__ SMemU sm;
    int tid = threadIdx.x;
    int bm = blockIdx.x << 7;
    int base = blockIdx.y << 10;
    int w = tid >> 6, lane = tid & 63;
    int l31 = lane & 31, l5 = lane >> 5, lo8 = lane << 3;
    int wr = w >> 1, wc = w & 1;
    int r = tid >> 1, q = tid & 1;

    float tv[6]; int ti[6];
    #pragma unroll
    for (int k=0;k<6;++k){ tv[k]=-INFINITY; ti[k]=0; }

    for (int bt = 0; bt < 4; ++bt){
        int bn = base + (bt<<8);
        f16f acc[2][4];
        #pragma unroll
        for (int a0=0;a0<2;++a0)
            #pragma unroll
            for (int a1=0;a1<4;++a1)
                #pragma unroll
                for (int e=0;e<16;++e) acc[a0][a1][e] = 0.f;

        for (int k0 = 0; k0 < 512; k0 += 32){
            __syncthreads();
            #pragma unroll
            for (int kf = 0; kf < 2; ++kf){
                int kk = k0 + (kf<<4) + (l5<<3);
                size_t ga = (size_t)(bm + (w<<5) + l31) * 512 + kk;
                gl_lds16(EHH + ga, &sm.t.Ah[((w<<1)+kf)<<9]);
                gl_lds16(EHL + ga, &sm.t.Al[((w<<1)+kf)<<9]);
                #pragma unroll
                for (int j = 0; j < 2; ++j){
                    int ct = (w<<1) + j;
                    size_t gb = (size_t)(bn + (ct<<5) + l31) * 512 + kk;
                    gl_lds16(ETH + gb, &sm.t.Bh[((ct<<1)+kf)<<9]);
                    gl_lds16(ETL + gb, &sm.t.Bl[((ct<<1)+kf)<<9]);
                }
            }
            __syncthreads();
            #pragma unroll
            for (int kf = 0; kf < 2; ++kf){
                s8v ah[2], al[2];
                #pragma unroll
                for (int rti=0;rti<2;++rti){
                    int fa = (((((wr<<1)+rti)<<1)+kf)<<9) + lo8;
                    ah[rti] = *(const s8v*)&sm.t.Ah[fa];
                    al[rti] = *(const s8v*)&sm.t.Al[fa];
                }
                #pragma unroll
                for (int cti=0;cti<4;++cti){
                    int fb = (((((wc<<2)+cti)<<1)+kf)<<9) + lo8;
                    s8v bh = *(const s8v*)&sm.t.Bh[fb];
                    s8v bl = *(const s8v*)&sm.t.Bl[fb];
                    #pragma unroll
                    for (int rti=0;rti<2;++rti){
                        acc[rti][cti] = MFMA32(ah[rti], bh, acc[rti][cti]);
                        acc[rti][cti] = MFMA32(ah[rti], bl, acc[rti][cti]);
                        acc[rti][cti] = MFMA32(al[rti], bh, acc[rti][cti]);
                    }
                }
            }
        }
        __syncthreads();
        // epilogue: 4 sub-halves of 64 cols; Sc column-major [64][132]
        #pragma unroll
        for (int s = 0; s < 4; ++s){
            if (wc == (s>>1)){
                #pragma unroll
                for (int cp=0;cp<2;++cp){
                    int cti = ((s&1)<<1) + cp;
                    int colw = ((cp<<5) + l31) * 132 + (wr<<6) + (l5<<2);
                    #pragma unroll
                    for (int rti=0;rti<2;++rti){
                        #pragma unroll
                        for (int g=0;g<4;++g){
                            float4 vv;
                            vv.x = acc[rti][cti][(g<<2)+0]*scale;
                            vv.y = acc[rti][cti][(g<<2)+1]*scale;
                            vv.z = acc[rti][cti][(g<<2)+2]*scale;
                            vv.w = acc[rti][cti][(g<<2)+3]*scale;
                            *(float4*)&sm.e.Sc[colw + (rti<<5) + (g<<3)] = vv;
                        }
                    }
                }
            }
            __syncthreads();
            int cbase = bn + (s<<6) + (q<<5);
            #pragma unroll
            for (int i=0;i<32;++i){
                float v = sm.e.Sc[(((q<<5)+i)*132) + r];
                if (v > tv[5]){
                    tv[5]=v; ti[5]=cbase+i;
                    #pragma unroll
                    for (int u=5;u>0;--u){
                        if (tv[u] > tv[u-1]){
                            float tf=tv[u]; tv[u]=tv[u-1]; tv[u-1]=tf;
                            int tg=ti[u]; ti[u]=ti[u-1]; ti[u-1]=tg;
                        }
                    }
                }
            }
            __syncthreads();
        }
    }
    // merge q halves -> per-block top6
    float* Mv = sm.e.Sc;
    int*   Mi = (int*)sm.e.Sc + 1536;
    #pragma unroll
    for (int k=0;k<6;++k){ Mv[r*12 + q*6 + k] = tv[k]; Mi[r*12 + q*6 + k] = ti[k]; }
    __syncthreads();
    if (tid < 128){
        int row = bm + tid;
        float* mv = &Mv[tid*12];
        int*   mi = &Mi[tid*12];
        unsigned used = 0;
        for (int k=0;k<6;++k){
            float bv=-INFINITY; int bc=0;
            for (int c=0;c<12;++c) if (!((used>>c)&1u) && mv[c] > bv){ bv=mv[c]; bc=c; }
            used |= 1u<<bc;
            VALS[(size_t)row*48 + blockIdx.y*6 + k] = bv;
            IDX [(size_t)row*48 + blockIdx.y*6 + k] = mi[bc];
        }
    }
}

// ---------------- KNN aggregation: 48-entry butterfly merge (R12-validated) ----------------
__global__ __launch_bounds__(256) void knn_agg(
    const u16* __restrict__ EHH, const u16* __restrict__ EHL,
    const u16* __restrict__ ETH, const u16* __restrict__ ETL,
    const float* __restrict__ VALS, const int* __restrict__ IDX,
    u16* __restrict__ ENH)
{
    int wave = threadIdx.x >> 6, lane = threadIdx.x & 63;
    int row = (blockIdx.x<<2) + wave;
    size_t vb = (size_t)row*48;
    float v0 = (lane < 48) ? VALS[vb + lane] : -INFINITY;
    int e0 = lane;
    float v[6]; int id[6];
    #pragma unroll
    for (int k=0;k<6;++k){
        float cv = v0; int ce = e0;
        #pragma unroll
        for (int off=1; off<64; off<<=1){
            float ov = __shfl_xor(cv, off, 64);
            int   oe = __shfl_xor(ce, off, 64);
            if (ov > cv || (ov == cv && oe < ce)){ cv=ov; ce=oe; }
        }
        v[k] = cv;
        id[k] = IDX[vb + ce];
        if (e0 == ce) v0 = -INFINITY;
    }
    float mx=v[0];
    #pragma unroll
    for (int k=1;k<6;++k) mx=fmaxf(mx,v[k]);
    float p[6], se=0.f;
    #pragma unroll
    for (int k=0;k<6;++k){ p[k]=expf(v[k]-mx); se+=p[k]; }
    float inv=1.f/se;
    #pragma unroll
    for (int k=0;k<6;++k) p[k]*=inv;

    size_t ro = (size_t)row*512;
    float e[8];
    #pragma unroll
    for (int j=0;j<8;++j){ int o = lane + (j<<6); e[j]=b2f(EHH[ro+o])+b2f(EHL[ro+o]); }
    float nb[6][8], sn[6], sg[6];
    #pragma unroll
    for (int k=0;k<6;++k){
        size_t no = (size_t)id[k]*512;
        float s_n=0.f, s_g=0.f;
        #pragma unroll
        for (int j=0;j<8;++j){
            int o = lane + (j<<6);
            float nv = b2f(ETH[no+o])+b2f(ETL[no+o]);
            nb[k][j]=nv;
            s_n += nv;
            float ehr_v = p[k]*nv + (1.f-p[k])*e[j];
            s_g += tanhf(e[j] + ehr_v);
        }
        #pragma unroll
        for (int o=1;o<64;o<<=1){ s_n += __shfl_xor(s_n,o,64); s_g += __shfl_xor(s_g,o,64); }
        sn[k]=s_n; sg[k]=s_g;
    }
    float ka[6];
    #pragma unroll
    for (int k=0;k<6;++k) ka[k]=sn[k]*sg[k];
    float km=ka[0];
    #pragma unroll
    for (int k=1;k<6;++k) km=fmaxf(km,ka[k]);
    float kp[6], ks=0.f;
    #pragma unroll
    for (int k=0;k<6;++k){ kp[k]=expf(ka[k]-km); ks+=kp[k]; }
    float kinv=1.f/ks;
    #pragma unroll
    for (int k=0;k<6;++k) kp[k]*=kinv;
    float o8[8]={0,0,0,0,0,0,0,0};
    #pragma unroll
    for (int k=0;k<6;++k)
        #pragma unroll
        for (int j=0;j<8;++j) o8[j] += kp[k]*nb[k][j];
    #pragma unroll
    for (int j=0;j<8;++j) ENH[ro + lane + (j<<6)] = f2b(o8[j]);
}

// ---------------- attention readout ----------------
__global__ __launch_bounds__(256) void att_g(
    const float* __restrict__ HM, const float* __restrict__ W2,
    const float* __restrict__ B2, float* __restrict__ G)
{
    int wave=threadIdx.x>>6, lane=threadIdx.x&63;
    int row=(blockIdx.x<<2)+wave;
    const float* hr = HM + (size_t)row*256;
    float s=0.f;
    #pragma unroll
    for (int j=0;j<4;++j) s += hr[lane+(j<<6)] * W2[lane+(j<<6)];
    #pragma unroll
    for (int o=1;o<64;o<<=1) s += __shfl_xor(s,o,64);
    if (lane==0) G[row] = s + B2[0];
}

__global__ __launch_bounds__(1024) void softg(float* __restrict__ G, float* __restrict__ EGP)
{
    __shared__ float red[1024];
    __shared__ float MS[2];
    int t=threadIdx.x;
    if (t < 512) EGP[t] = 0.f;   // zero e_g accumulator for eg_at atomics (R15-validated)
    float m=-INFINITY;
    for (int i=t;i<8192;i+=1024) m=fmaxf(m,G[i]);
    red[t]=m; __syncthreads();
    for (int o=512;o>0;o>>=1){ if(t<o) red[t]=fmaxf(red[t],red[t+o]); __syncthreads(); }
    if (t==0) MS[0]=red[0];
    __syncthreads();
    float M=MS[0], s=0.f;
    for (int i=t;i<8192;i+=1024) s += expf(G[i]-M);
    red[t]=s; __syncthreads();
    for (int o=512;o>0;o>>=1){ if(t<o) red[t]+=red[t+o]; __syncthreads(); }
    if (t==0) MS[1]=red[0];
    __syncthreads();
    float inv=1.f/MS[1];
    for (int i=t;i<8192;i+=1024) G[i] = expf(G[i]-M)*inv;
}

// coalesced e_g: row-panel partials + atomics (EGP pre-zeroed by softg; R15-validated)
__global__ __launch_bounds__(256) void eg_at(
    const float* __restrict__ A, const float* __restrict__ X, float* __restrict__ OUT)
{
    int b = blockIdx.x, t = threadIdx.x;
    float s0=0.f, s1=0.f;
    for (int r=0;r<64;++r){
        int row = b*64 + r;
        float a = A[row];
        const float* xr = X + (size_t)row*512;
        s0 += a * xr[t];
        s1 += a * xr[t+256];
    }
    atomicAdd(&OUT[t], s0);
    atomicAdd(&OUT[t+256], s1);
}

// ---------------- launch ----------------
extern "C" void kernel_launch(void* const* d_in, const int* in_sizes, int n_in,
                              void* d_out, int out_size, void* d_ws, size_t ws_size,
                              hipStream_t stream)
{
    (void)n_in; (void)out_size; (void)ws_size;
    static const int ss[6] = {89,334,534,471,1510,482};

    bool sig_order = (in_sizes[12] == 1536);
    OmicArgs oa;
    const float *sb1, *sw2, *sb2, *xpath;
    if (sig_order) {
        for (int i=0;i<6;++i){ oa.x[i]=(const float*)d_in[i]; oa.w1[i]=(const float*)d_in[6+i]; oa.s[i]=ss[i]; }
        sb1   = (const float*)d_in[12];
        sw2   = (const float*)d_in[13];
        sb2   = (const float*)d_in[14];
        xpath = (const float*)d_in[15];
    } else {
        for (int i=0;i<6;++i){ oa.x[i]=(const float*)d_in[2*i]; oa.w1[i]=(const float*)d_in[2*i+1]; oa.s[i]=ss[i]; }
        xpath = (const float*)d_in[12];
        sb1   = (const float*)d_in[13];
        sw2   = (const float*)d_in[14];
        sb2   = (const float*)d_in[15];
    }
    const float* fc1w = (const float*)d_in[16];
    const float* fc1b = (const float*)d_in[17];
    const float* whw  = (const float*)d_in[18];
    const float* whb  = (const float*)d_in[19];
    const float* wtw  = (const float*)d_in[20];
    const float* wtb  = (const float*)d_in[21];
    const float* l1w  = (const float*)d_in[22];
    const float* l1b  = (const float*)d_in[23];
    const float* l2w  = (const float*)d_in[24];
    const float* l2b  = (const float*)d_in[25];
    const float* aw1  = (const float*)d_in[26];
    const float* ab1  = (const float*)d_in[27];
    const float* aw2  = (const float*)d_in[28];
    const float* ab2  = (const float*)d_in[29];

    float* out = (float*)d_out;            // fp32: e_omic(1536) | e_h2(8192*512) | e_g(512)
    float* eh2 = out + 1536;
    float* egp = out + 1536 + 4194304;

    // Lifetimes in the e_h2 output region: h fp32 [fc1 .. wh/wt], then vals/idx
    // [logits .. knn] (R12-validated offsets, 48/row), then final e_h2 [lin12 ..].
    float* h    = eh2;
    float* vals = eh2;                     // 8192*48 floats
    int*   idxb = (int*)(eh2 + 786432);    // 8192*48 ints

    char* wsb = (char*)d_ws;
    u16* ehh = (u16*)wsb;                               // 8 MB
    u16* ehl = ehh + 4194304;                           // 8 MB
    u16* eth = ehl + 4194304;                           // 8 MB (later hm fp32)
    u16* etl = eth + 4194304;                           // 8 MB
    u16* enh = etl + 4194304;                           // 8 MB (bf16)
    u16* wreg = enh + 4194304;                          // 4 MB weight splits
    u16* fc1h = wreg,            *fc1l = wreg +  196608;
    u16* whh  = wreg +  393216,  *whl  = wreg +  655360;
    u16* wth  = wreg +  917504,  *wtl  = wreg + 1179648;
    u16* l1bf = wreg + 1441792,  *l2bf = wreg + 1703936;
    u16* awbf = wreg + 1966080;                         // ends at wreg+2097152
    float* mcol = (float*)(wsb + 48234496);             // 512 (R12-validated offset)
    float* gbuf = mcol + 512;                           // 8192
    float* hm   = (float*)eth;

    omic_kernel<<<6,256,0,stream>>>(oa, sb1, sw2, sb2, out);

    WcArgs wa;
    wa.seg[0] = { fc1w, fc1h, fc1l, 196608 };
    wa.seg[1] = { whw,  whh,  whl,  262144 };
    wa.seg[2] = { wtw,  wth,  wtl,  262144 };
    wa.seg[3] = { l1w,  l1bf, nullptr, 262144 };
    wa.seg[4] = { l2w,  l2bf, nullptr, 262144 };
    wa.seg[5] = { aw1,  awbf, nullptr, 131072 };
    wconv<<<dim3(16,6),256,0,stream>>>(wa);

    gemm_mfma<1,0><<<dim3(64,4),256,0,stream>>>(xpath, fc1h, fc1l, fc1b,
        h, nullptr, nullptr, 8192,512,384);
    colmean<<<512,256,0,stream>>>(h, mcol);
    hupd<<<16384,256,0,stream>>>(h, mcol);
    gemm_mfma<1,1><<<dim3(64,4),256,0,stream>>>(h, whh, whl, whb,
        nullptr, ehh, ehl, 8192,512,512);
    gemm_mfma<1,1><<<dim3(64,4),256,0,stream>>>(h, wth, wtl, wtb,
        nullptr, eth, etl, 8192,512,512);
    logits_topk_mfma<<<dim3(64,8),256,0,stream>>>(ehh, ehl, eth, etl, vals, idxb);
    knn_agg<<<2048,256,0,stream>>>(ehh, ehl, eth, etl, vals, idxb, enh);
    lin12_mfma<<<dim3(64,4),256,0,stream>>>(ehh, ehl, enh, l1bf, l1b, l2bf, l2b, eh2);
    gemm_mfma<0,0><<<dim3(64,2),256,0,stream>>>(eh2, awbf, awbf, ab1,
        hm, nullptr, nullptr, 8192,256,512);
    att_g<<<2048,256,0,stream>>>(hm, aw2, ab2, gbuf);
    softg<<<1,1024,0,stream>>>(gbuf, egp);
    eg_at<<<128,256,0,stream>>>(gbuf, eh2, egp);
}